// Round 1
// baseline (268.150 us; speedup 1.0000x reference)
//
#include <hip/hip_runtime.h>
#include <math.h>

// Problem constants (fixed by setup_inputs)
#define NB 4      // batch
#define NH 8      // heads
#define NN 4096   // seq len
#define ND 64     // dim
#define NK 16     // K2
#define MM 8192   // 2N (FFT length)
#define LOG2M 13
#define NT 512    // threads per block

// ---- radix-2 DIF: natural input -> bit-reversed output, forward (e^-i) ----
__device__ __forceinline__ void fft_dif(float2* A, int tid) {
    for (int s = LOG2M - 1; s >= 0; --s) {
        __syncthreads();
        const int half = 1 << s;
        const float cmul = -(float)M_PI / (float)half;
        #pragma unroll 1
        for (int b = tid; b < MM / 2; b += NT) {
            int pos = b & (half - 1);
            int i0  = ((b >> s) << (s + 1)) + pos;
            int i1  = i0 + half;
            float2 u = A[i0];
            float2 v = A[i1];
            float sn, cs;
            __sincosf(cmul * (float)pos, &sn, &cs);
            float2 t = make_float2(u.x - v.x, u.y - v.y);
            A[i0] = make_float2(u.x + v.x, u.y + v.y);
            A[i1] = make_float2(t.x * cs - t.y * sn, t.x * sn + t.y * cs);
        }
    }
    __syncthreads();
}

// ---- radix-2 DIT: bit-reversed input -> natural output, inverse (e^+i), unnormalized ----
__device__ __forceinline__ void fft_dit_inv(float2* A, int tid) {
    for (int s = 0; s < LOG2M; ++s) {
        __syncthreads();
        const int half = 1 << s;
        const float cmul = (float)M_PI / (float)half;
        #pragma unroll 1
        for (int b = tid; b < MM / 2; b += NT) {
            int pos = b & (half - 1);
            int i0  = ((b >> s) << (s + 1)) + pos;
            int i1  = i0 + half;
            float2 u = A[i0];
            float2 v = A[i1];
            float sn, cs;
            __sincosf(cmul * (float)pos, &sn, &cs);
            float2 t = make_float2(v.x * cs - v.y * sn, v.x * sn + v.y * cs);
            A[i1] = make_float2(u.x - t.x, u.y - t.y);
            A[i0] = make_float2(u.x + t.x, u.y + t.y);
        }
    }
    __syncthreads();
}

__global__ __launch_bounds__(NT, 1)
void fftconv_kernel(const float* __restrict__ x,
                    const float* __restrict__ decay,
                    const float* __restrict__ cosb,
                    const float* __restrict__ coef,
                    float* __restrict__ out)
{
    __shared__ float2 V[MM];   // filter spectrum (bitrev order after DIF)
    __shared__ float2 X[MM];   // work buffer

    // XCD swizzle: 512 wgs / 8 XCDs -> all 64 d-channels of one h land on
    // the same XCD (its L2 then serves the stride-64 x/out lines once).
    int bid = blockIdx.x;
    int wg  = (bid & 7) * 64 + (bid >> 3);
    int h   = wg >> 6;   // [0,8)
    int d   = wg & 63;   // [0,64)
    int tid = threadIdx.x;

    // ---- Phase A: a[u] = decay[u] * sum_k coef[h,k,d] * cos[u,k] ----
    float cf[NK];
    #pragma unroll
    for (int k = 0; k < NK; ++k)
        cf[k] = coef[(h * NK + k) * ND + d];   // wave-uniform

    for (int u = tid; u < MM; u += NT) {
        const float4* cr = (const float4*)(cosb + (size_t)u * NK);
        float4 c0 = cr[0], c1 = cr[1], c2 = cr[2], c3 = cr[3];
        float acc = c0.x*cf[0]  + c0.y*cf[1]  + c0.z*cf[2]  + c0.w*cf[3]
                  + c1.x*cf[4]  + c1.y*cf[5]  + c1.z*cf[6]  + c1.w*cf[7]
                  + c2.x*cf[8]  + c2.y*cf[9]  + c2.z*cf[10] + c2.w*cf[11]
                  + c3.x*cf[12] + c3.y*cf[13] + c3.z*cf[14] + c3.w*cf[15];
        V[u] = make_float2(decay[u] * acc, 0.0f);
    }

    // ---- forward FFT of filter (syncs internally; first sync covers Phase A) ----
    fft_dif(V, tid);

    // ---- two batch-pairs: conv(x_b0, a) + i*conv(x_b1, a) via one complex FFT ----
    const float inv_m = 1.0f / (float)MM;
    for (int bp = 0; bp < 2; ++bp) {
        const int b0 = 2 * bp, b1 = 2 * bp + 1;
        const float* x0 = x + ((size_t)(b0 * NH + h) * NN) * ND + d;
        const float* x1 = x + ((size_t)(b1 * NH + h) * NN) * ND + d;

        __syncthreads();  // previous use of X fully drained
        for (int u = tid; u < NN; u += NT)
            X[u] = make_float2(x0[(size_t)u * ND], x1[(size_t)u * ND]);
        for (int u = NN + tid; u < MM; u += NT)
            X[u] = make_float2(0.0f, 0.0f);

        fft_dif(X, tid);   // X now bitrev spectrum

        // pointwise complex multiply (both arrays share the same bitrev order)
        for (int u = tid; u < MM; u += NT) {
            float2 a_ = X[u], f_ = V[u];
            X[u] = make_float2(a_.x * f_.x - a_.y * f_.y,
                               a_.x * f_.y + a_.y * f_.x);
        }

        fft_dit_inv(X, tid);  // natural-order time domain (unnormalized)

        float* o0 = out + ((size_t)(b0 * NH + h) * NN) * ND + d;
        float* o1 = out + ((size_t)(b1 * NH + h) * NN) * ND + d;
        for (int u = tid; u < NN; u += NT) {
            float2 z = X[u];
            o0[(size_t)u * ND] = z.x * inv_m;
            o1[(size_t)u * ND] = z.y * inv_m;
        }
    }
}

extern "C" void kernel_launch(void* const* d_in, const int* in_sizes, int n_in,
                              void* d_out, int out_size, void* d_ws, size_t ws_size,
                              hipStream_t stream) {
    const float* x     = (const float*)d_in[0];
    const float* decay = (const float*)d_in[1];
    const float* cosb  = (const float*)d_in[2];
    const float* coef  = (const float*)d_in[3];
    // d_in[4] = index = arange(N): identity take, handled implicitly.
    float* out = (float*)d_out;

    hipLaunchKernelGGL(fftconv_kernel, dim3(NH * ND), dim3(NT), 0, stream,
                       x, decay, cosb, coef, out);
}